// Round 16
// baseline (25.538 us; speedup 1.0000x reference)
//
#include <hip/hip_runtime.h>
#include <math.h>

#define NPTS 4096
#define BLK 256
#define PAIR_BLOCKS 4352   // sum_{jg=0}^{15} 32*(jg+1): upper-triangle 8x256 tiles
#define VB 8               // i-values per block (consecutive, block-uniform)
#define NGL 5              // Gauss-Legendre nodes

#define SQRT_LOG2E 1.2011224087864498f
#define LOG2E      1.4426950408889634f

#define TAB_BYTES (NPTS * 16)   // float4 table in d_ws; partials follow

// raw v_exp_f32 (D = 2^S0) — exp2f() is libm (slow); __expf adds a v_mul.
__device__ __forceinline__ float fast_exp2(float x) {
#if __has_builtin(__builtin_amdgcn_exp2f)
    return __builtin_amdgcn_exp2f(x);
#else
    float r;
    asm("v_exp_f32 %0, %1" : "=v"(r) : "v"(x));
    return r;
#endif
}

// ---------------- block-level float reduction (deterministic) ----------------
__device__ __forceinline__ float block_reduce_f(float v) {
    #pragma unroll
    for (int off = 32; off > 0; off >>= 1)
        v += __shfl_down(v, off, 64);
    __shared__ float smem[BLK / 64];
    const int lane = threadIdx.x & 63;
    const int wid  = threadIdx.x >> 6;
    if (lane == 0) smem[wid] = v;
    __syncthreads();
    float t = 0.f;
    if (threadIdx.x == 0) {
        #pragma unroll
        for (int w = 0; w < BLK / 64; ++w) t += smem[w];
    }
    return t;  // valid in thread 0 only
}

// ---------------- kernel 0: build interleaved float4 table ----------------
__global__ __launch_bounds__(BLK) void build_tab(const float2* __restrict__ z0,
                                                 const float2* __restrict__ v0,
                                                 float4* __restrict__ tab) {
    const int i = blockIdx.x * BLK + threadIdx.x;   // 16*256 = 4096
    const float2 z = z0[i];
    const float2 v = v0[i];
    tab[i] = make_float4(z.x, z.y, v.x, v.y);
}

// ---------------- pair tile body: 8 uniform i x 256 lane j; GL-5 quadrature ----
// integrand: exp(beta - (a+m t)^2 - (bb+n t)^2), t in [t0,tn]; pre-scaled by
// sqrt(log2e) so the exp2 needs no per-node multiply.
template<bool MIXED>
__device__ __forceinline__ float pair_body(const float2* __restrict__ z0,
                                           const float2* __restrict__ v0,
                                           const float4* __restrict__ tab,
                                           int ibase, int j,
                                           const float* tnode, const float* wnode,
                                           float Bt) {
    const float4 tj = tab[j];              // per-lane, coalesced, 1 dwordx4

    // ---- stage 1: diffs + pre-scale (i-side SGPR broadcasts) ----
    float as[VB], bs[VB], ms[VB], ns[VB];
    #pragma unroll
    for (int k = 0; k < VB; ++k) {
        const float2 zi = z0[ibase + k];   // block-uniform -> s_load broadcast
        const float2 vi = v0[ibase + k];
        as[k] = (zi.x - tj.x) * SQRT_LOG2E;
        bs[k] = (zi.y - tj.y) * SQRT_LOG2E;
        ms[k] = (vi.x - tj.z) * SQRT_LOG2E;
        ns[k] = (vi.y - tj.w) * SQRT_LOG2E;
    }

    // ---- stage 2: 5-node GL quadrature, 8 independent chains ----
    float acc = 0.f;
    #pragma unroll
    for (int k = 0; k < VB; ++k) {
        float pacc = 0.f;
        #pragma unroll
        for (int nd = 0; nd < NGL; ++nd) {
            const float u   = fmaf(ms[k], tnode[nd], as[k]);
            const float w   = fmaf(ns[k], tnode[nd], bs[k]);
            const float arg = fmaf(-u, u, fmaf(-w, w, Bt));
            const float E   = fast_exp2(arg);
            pacc = fmaf(wnode[nd], E, pacc);
        }
        if (MIXED) acc += (ibase + k < j) ? pacc : 0.f;   // mask kills i>=j (incl. diagonal)
        else       acc += pacc;                            // pure: i<j guaranteed
    }
    return acc;
}

// ---------------- fused kernel: every block = pair tile + 1 event/thread ----
__global__ __launch_bounds__(BLK) void fused_kernel(
        const int* __restrict__ eu, const int* __restrict__ ev,
        const float* __restrict__ et,
        const float2* __restrict__ z0, const float2* __restrict__ v0,
        const float4* __restrict__ tab,
        const float* __restrict__ beta_p, const float* __restrict__ t0_p,
        const float* __restrict__ tn_p,
        float* __restrict__ partials, int nE) {
    const int pair_id = blockIdx.x;                  // [0, PAIR_BLOCKS)

    // ---- event: issue index/time loads FIRST (HBM latency hides under setup) ----
    const int  eidx = pair_id * BLK + threadIdx.x;   // 4352*256 >= 1e6
    const bool eact = (eidx < nE);
    const int  safe = eact ? eidx : 0;
    const int   u_i = eu[safe];                      // issue
    const int   w_i = ev[safe];                      // issue
    const float t_e = et[safe];                      // issue

    // ---- pair setup: uniform scalars + triangle inversion (covers latency) ----
    const float b  = beta_p[0];
    const float t0 = t0_p[0];
    const float tn = tn_p[0];
    const float dt = tn - t0;
    const float Bt = b * LOG2E;

    float tnode[NGL], wnode[NGL];
    tnode[0] = fmaf(dt, 0.04691007703066800f, t0); wnode[0] = dt * 0.11846344252809454f;
    tnode[1] = fmaf(dt, 0.23076534494715845f, t0); wnode[1] = dt * 0.23931433524968324f;
    tnode[2] = fmaf(dt, 0.5f,                 t0); wnode[2] = dt * 0.28444444444444444f;
    tnode[3] = fmaf(dt, 0.76923465505284155f, t0); wnode[3] = dt * 0.23931433524968324f;
    tnode[4] = fmaf(dt, 0.95308992296933200f, t0); wnode[4] = dt * 0.11846344252809454f;

    // invert triangular index: cum(jg) = 16*jg*(jg+1) blocks before group jg
    const int P = pair_id >> 4;                      // [0, 272)
    int jg = (int)((sqrtf((float)(4 * P + 1)) - 1.0f) * 0.5f);
    while ((jg + 1) * (jg + 2) <= P) ++jg;           // integer correction
    while (jg * (jg + 1) > P) --jg;
    const int ic    = pair_id - 16 * jg * (jg + 1);  // [0, 32*(jg+1))
    const int ibase = ic << 3;                       // 8 consecutive i
    const int j     = (jg << 8) | threadIdx.x;       // per-lane, coalesced

    // ---- event: 2 float4 gathers (indices arrived; u=w=0 when masked -> d2=0) ----
    float acc;
    {
        const float4 A = tab[u_i];
        const float4 B = tab[w_i];
        const float dx = fmaf(A.z - B.z, t_e, A.x - B.x);
        const float dy = fmaf(A.w - B.w, t_e, A.y - B.y);
        acc = fmaf(dx, dx, dy * dy);                 // == 0 for masked slots
    }

    // ---- pair tile ----
    if (ic < 32 * jg) acc += pair_body<false>(z0, v0, tab, ibase, j, tnode, wnode, Bt);
    else              acc += pair_body<true >(z0, v0, tab, ibase, j, tnode, wnode, Bt);

    const float r = block_reduce_f(acc);
    if (threadIdx.x == 0) partials[pair_id] = r;
}

// ---------------- final combine (double precision, deterministic) ----------------
__global__ void final_kernel(const float* __restrict__ pp,
                             const float* __restrict__ beta_p, float* __restrict__ out,
                             int nE) {
    __shared__ double sd[BLK];
    double s = 0.0;
    #pragma unroll
    for (int k = 0; k < PAIR_BLOCKS / BLK; ++k)      // 17 fixed-order slots/thread
        s += (double)pp[threadIdx.x + k * BLK];
    sd[threadIdx.x] = s;
    __syncthreads();
    for (int st = BLK / 2; st > 0; st >>= 1) {
        if (threadIdx.x < st) sd[threadIdx.x] += sd[threadIdx.x + st];
        __syncthreads();
    }
    if (threadIdx.x == 0) {
        out[0] = (float)((double)nE * (double)beta_p[0] - sd[0]);
    }
}

extern "C" void kernel_launch(void* const* d_in, const int* in_sizes, int n_in,
                              void* d_out, int out_size, void* d_ws, size_t ws_size,
                              hipStream_t stream) {
    const int*    eu   = (const int*)d_in[0];
    const int*    ev   = (const int*)d_in[1];
    const float*  et   = (const float*)d_in[2];
    const float*  t0   = (const float*)d_in[3];
    const float*  tn   = (const float*)d_in[4];
    const float*  beta = (const float*)d_in[5];
    const float2* z0   = (const float2*)d_in[6];
    const float2* v0   = (const float2*)d_in[7];
    float* out = (float*)d_out;
    const int nE = in_sizes[0];

    float4* tab      = (float4*)d_ws;                       // 64 KB interleaved table
    float*  partials = (float*)((char*)d_ws + TAB_BYTES);   // PAIR_BLOCKS floats

    build_tab<<<NPTS / BLK, BLK, 0, stream>>>(z0, v0, tab);
    fused_kernel<<<PAIR_BLOCKS, BLK, 0, stream>>>(eu, ev, et, z0, v0, tab,
                                                  beta, t0, tn, partials, nE);
    final_kernel<<<1, BLK, 0, stream>>>(partials, beta, out, nE);
}

// Round 17
// 19.929 us; speedup vs baseline: 1.2814x; 1.2814x over previous
//
#include <hip/hip_runtime.h>
#include <math.h>

#define NPTS 4096
#define BLK 256
#define PAIR_BLOCKS 4352   // sum_{jg=0}^{15} 32*(jg+1): upper-triangle 8x256 tiles
#define VB 4               // ILP batch width (two halves of the 8-row tile)
#define NGL 5              // Gauss-Legendre nodes

#define LOG2E 1.4426950408889634f

// raw v_exp_f32 (D = 2^S0) — exp2f() is libm (slow); __expf adds a v_mul.
__device__ __forceinline__ float fast_exp2(float x) {
#if __has_builtin(__builtin_amdgcn_exp2f)
    return __builtin_amdgcn_exp2f(x);
#else
    float r;
    asm("v_exp_f32 %0, %1" : "=v"(r) : "v"(x));
    return r;
#endif
}

// ---------------- block-level float reduction (deterministic) ----------------
__device__ __forceinline__ float block_reduce_f(float v) {
    #pragma unroll
    for (int off = 32; off > 0; off >>= 1)
        v += __shfl_down(v, off, 64);
    __shared__ float smem[BLK / 64];
    const int lane = threadIdx.x & 63;
    const int wid  = threadIdx.x >> 6;
    if (lane == 0) smem[wid] = v;
    __syncthreads();
    float t = 0.f;
    if (threadIdx.x == 0) {
        #pragma unroll
        for (int w = 0; w < BLK / 64; ++w) t += smem[w];
    }
    return t;  // valid in thread 0 only
}

// ---------------- half-tile body: 4 uniform i x 256 lane j; GL-5 quadrature ----
// arg(t) = log2e*(b - (a+mt)^2 - (bb+nt)^2) = c0 + c1 t + c2 t^2 (Horner).
template<bool MIXED>
__device__ __forceinline__ float pair_half(const float2* __restrict__ z0,
                                           const float2* __restrict__ v0,
                                           int ibase, int j,
                                           float zjx, float zjy, float vjx, float vjy,
                                           const float* tnode, const float* wnode,
                                           float b) {
    // ---- per-pair Horner coefficients (i-side SGPR broadcasts) ----
    float c0[VB], c1[VB], c2[VB];
    #pragma unroll
    for (int k = 0; k < VB; ++k) {
        const float2 zi = z0[ibase + k];   // block-uniform -> s_load broadcast
        const float2 vi = v0[ibase + k];
        const float a  = zi.x - zjx;
        const float bb = zi.y - zjy;
        const float m  = vi.x - vjx;
        const float n  = vi.y - vjy;
        c2[k] = fmaf(m, m, n * n) * (-LOG2E);
        c1[k] = fmaf(a, m, bb * n) * (-2.0f * LOG2E);
        c0[k] = fmaf(-a, a, fmaf(-bb, bb, b)) * LOG2E;
    }

    // ---- 5-node GL quadrature, 4 independent chains ----
    float acc = 0.f;
    #pragma unroll
    for (int k = 0; k < VB; ++k) {
        float pacc = 0.f;
        #pragma unroll
        for (int nd = 0; nd < NGL; ++nd) {
            const float h   = fmaf(c2[k], tnode[nd], c1[k]);
            const float arg = fmaf(h, tnode[nd], c0[k]);
            const float E   = fast_exp2(arg);
            pacc = fmaf(wnode[nd], E, pacc);
        }
        if (MIXED) acc += (ibase + k < j) ? pacc : 0.f;   // mask kills i>=j (incl. diagonal)
        else       acc += pacc;                            // pure: i<j guaranteed
    }
    return acc;
}

// ---------------- fused kernel: every block = pair tile + 1 event/thread ----
__global__ __launch_bounds__(BLK) void fused_kernel(
        const int* __restrict__ eu, const int* __restrict__ ev,
        const float* __restrict__ et,
        const float2* __restrict__ z0, const float2* __restrict__ v0,
        const float* __restrict__ beta_p, const float* __restrict__ t0_p,
        const float* __restrict__ tn_p,
        float* __restrict__ partials, int nE) {
    const int pair_id = blockIdx.x;                  // [0, PAIR_BLOCKS)

    // ---- event: issue index/time loads FIRST (HBM latency hides under setup) ----
    const int  eidx = pair_id * BLK + threadIdx.x;   // 4352*256 >= 1e6
    const bool eact = (eidx < nE);
    const int  safe = eact ? eidx : 0;
    const int   u_i = eu[safe];                      // issue
    const int   w_i = ev[safe];                      // issue
    const float t_e = et[safe];                      // issue

    // ---- pair setup: uniform scalars + triangle inversion (covers latency) ----
    const float b  = beta_p[0];
    const float t0 = t0_p[0];
    const float tn = tn_p[0];
    const float dt = tn - t0;

    float tnode[NGL], wnode[NGL];
    tnode[0] = fmaf(dt, 0.04691007703066800f, t0); wnode[0] = dt * 0.11846344252809454f;
    tnode[1] = fmaf(dt, 0.23076534494715845f, t0); wnode[1] = dt * 0.23931433524968324f;
    tnode[2] = fmaf(dt, 0.5f,                 t0); wnode[2] = dt * 0.28444444444444444f;
    tnode[3] = fmaf(dt, 0.76923465505284155f, t0); wnode[3] = dt * 0.23931433524968324f;
    tnode[4] = fmaf(dt, 0.95308992296933200f, t0); wnode[4] = dt * 0.11846344252809454f;

    // invert triangular index: cum(jg) = 16*jg*(jg+1) blocks before group jg
    const int P = pair_id >> 4;                      // [0, 272)
    int jg = (int)((sqrtf((float)(4 * P + 1)) - 1.0f) * 0.5f);
    while ((jg + 1) * (jg + 2) <= P) ++jg;           // integer correction
    while (jg * (jg + 1) > P) --jg;
    const int ic    = pair_id - 16 * jg * (jg + 1);  // [0, 32*(jg+1))
    const int ibase = ic << 3;                       // 8 consecutive i
    const int j     = (jg << 8) | threadIdx.x;       // per-lane, coalesced

    const float2 zj = z0[j], vj = v0[j];             // per-lane, coalesced, hoisted

    // ---- event: gathers + d2 (indices arrived; u=w=0 when masked -> d2=0) ----
    float acc;
    {
        const float2 za = z0[u_i], zb = z0[w_i];
        const float2 va = v0[u_i], vb = v0[w_i];
        const float dx = fmaf(va.x - vb.x, t_e, za.x - zb.x);
        const float dy = fmaf(va.y - vb.y, t_e, za.y - zb.y);
        acc = fmaf(dx, dx, dy * dy);                 // == 0 for masked slots
    }

    // ---- pair tile: two VB=4 halves (register-lean -> 8 waves/SIMD target) ----
    if (ic < 32 * jg) {
        acc += pair_half<false>(z0, v0, ibase,     j, zj.x, zj.y, vj.x, vj.y, tnode, wnode, b);
        acc += pair_half<false>(z0, v0, ibase + 4, j, zj.x, zj.y, vj.x, vj.y, tnode, wnode, b);
    } else {
        acc += pair_half<true >(z0, v0, ibase,     j, zj.x, zj.y, vj.x, vj.y, tnode, wnode, b);
        acc += pair_half<true >(z0, v0, ibase + 4, j, zj.x, zj.y, vj.x, vj.y, tnode, wnode, b);
    }

    const float r = block_reduce_f(acc);
    if (threadIdx.x == 0) partials[pair_id] = r;
}

// ---------------- final combine (double precision, deterministic) ----------------
__global__ void final_kernel(const float* __restrict__ pp,
                             const float* __restrict__ beta_p, float* __restrict__ out,
                             int nE) {
    __shared__ double sd[BLK];
    double s = 0.0;
    #pragma unroll
    for (int k = 0; k < PAIR_BLOCKS / BLK; ++k)      // 17 fixed-order slots/thread
        s += (double)pp[threadIdx.x + k * BLK];
    sd[threadIdx.x] = s;
    __syncthreads();
    for (int st = BLK / 2; st > 0; st >>= 1) {
        if (threadIdx.x < st) sd[threadIdx.x] += sd[threadIdx.x + st];
        __syncthreads();
    }
    if (threadIdx.x == 0) {
        out[0] = (float)((double)nE * (double)beta_p[0] - sd[0]);
    }
}

extern "C" void kernel_launch(void* const* d_in, const int* in_sizes, int n_in,
                              void* d_out, int out_size, void* d_ws, size_t ws_size,
                              hipStream_t stream) {
    const int*    eu   = (const int*)d_in[0];
    const int*    ev   = (const int*)d_in[1];
    const float*  et   = (const float*)d_in[2];
    const float*  t0   = (const float*)d_in[3];
    const float*  tn   = (const float*)d_in[4];
    const float*  beta = (const float*)d_in[5];
    const float2* z0   = (const float2*)d_in[6];
    const float2* v0   = (const float2*)d_in[7];
    float* out = (float*)d_out;
    const int nE = in_sizes[0];

    float* partials = (float*)d_ws;                  // PAIR_BLOCKS floats

    fused_kernel<<<PAIR_BLOCKS, BLK, 0, stream>>>(eu, ev, et, z0, v0, beta, t0, tn,
                                                  partials, nE);
    final_kernel<<<1, BLK, 0, stream>>>(partials, beta, out, nE);
}